// Round 5
// baseline (96.897 us; speedup 1.0000x reference)
//
#include <hip/hip_runtime.h>

// Weighted Chamfer, B=4, N=M=8192, D=3, fp32 in/out.
// out = (1/B)*[ sum_b sum_n w*min_m d2 + sum_b sum_m min_n d2 ]
//
// One v_mfma_f32_32x32x16_bf16 yields a 32x32 tile of d2 = s2 + t2 - 2 s.t
// via K-slot packing with split-bf16 compensation (verified rounds 2-4):
//   k0-8: {hs,hs,ls}x * {-2ht,-2lt,-2ht}x per dim; k9-10: {h,l}(s2)*1;
//   k11-12: 1*{h,l}(t2); k13-15: zero.  Error ~1e-5 (threshold 5.76).
// C/D layout (m74/m101): col=lane&31, row=(reg&3)+8*(reg>>2)+4*(lane>>5).
//
// Round 5: RF=4 (8 MFMA per 2 ds_read_b128), double-buffered LDS stages with
// register prefetch (staging hidden behind compute), __launch_bounds__(256,2)
// so ~230 live VGPRs stay architectural (r3 showed AGPR-split = 3.8x VALU tax).
// Note: harness re-poison of d_ws (256 MB fill, ~42 us) dominates dur_us floor.

typedef short bf16x8 __attribute__((ext_vector_type(8)));
typedef float f32x16 __attribute__((ext_vector_type(16)));

#define BB 4
#define NP 8192
#define NFRAG (NP / 32)          // 256 32-row fragments per batch
#define RF 4                     // row-frags per wave (128 rows)
#define WAVES 4                  // 512 rows per block
#define RBLOCKS 16               // 8192 / 512
#define CFRAGS 16                // frags per LDS stage (512 cols, 16 KB)
#define NSTAGE 4                 // stages per block -> 2048 cols
#define NCHG 4                   // column groups (8192 / 2048)

__device__ __forceinline__ unsigned short bf16r(float x) {
    unsigned u = __float_as_uint(x);
    unsigned r = u + 0x7FFFu + ((u >> 16) & 1u);
    return (unsigned short)(r >> 16);
}
__device__ __forceinline__ float bf16f(unsigned short h) {
    return __uint_as_float(((unsigned)h) << 16);
}

// ---- prep: A-pack and B-pack (32x32x16 fragment layout) for both clouds ----
__global__ __launch_bounds__(256) void prep_kernel(
    const float* __restrict__ src, const float* __restrict__ tgt,
    uint4* __restrict__ aS, uint4* __restrict__ bS,
    uint4* __restrict__ aT, uint4* __restrict__ bT,
    float* __restrict__ out)
{
    int gid = blockIdx.x * 256 + threadIdx.x;   // 2*4*256*64 = 131072
    if (gid == 0) out[0] = 0.0f;
    int cloud = gid >> 16;
    int rem   = gid & 65535;
    int b     = rem >> 14;
    int f     = (rem >> 6) & (NFRAG - 1);
    int lane  = rem & 63;
    int half  = lane >> 5;
    int p     = f * 32 + (lane & 31);

    const float* c = cloud ? tgt : src;
    size_t base = ((size_t)b * NP + p) * 3;
    float x = c[base + 0], y = c[base + 1], z = c[base + 2];
    float n2 = x * x + y * y + z * z;

    unsigned short hx = bf16r(x), lx = bf16r(x - bf16f(hx));
    unsigned short hy = bf16r(y), ly = bf16r(y - bf16f(hy));
    unsigned short hz = bf16r(z), lz = bf16r(z - bf16f(hz));
    unsigned short h2 = bf16r(n2), l2 = bf16r(n2 - bf16f(h2));
    unsigned short nhx = bf16r(-2.f * bf16f(hx)), nlx = bf16r(-2.f * bf16f(lx));
    unsigned short nhy = bf16r(-2.f * bf16f(hy)), nly = bf16r(-2.f * bf16f(ly));
    unsigned short nhz = bf16r(-2.f * bf16f(hz)), nlz = bf16r(-2.f * bf16f(lz));
    const unsigned ONE = 0x3F80u;

    uint4 pa, pb;
    if (half == 0) {   // k = 0..7
        pa.x = (unsigned)hx | ((unsigned)hx << 16);
        pa.y = (unsigned)lx | ((unsigned)hy << 16);
        pa.z = (unsigned)hy | ((unsigned)ly << 16);
        pa.w = (unsigned)hz | ((unsigned)hz << 16);
        pb.x = (unsigned)nhx | ((unsigned)nlx << 16);
        pb.y = (unsigned)nhx | ((unsigned)nhy << 16);
        pb.z = (unsigned)nly | ((unsigned)nhy << 16);
        pb.w = (unsigned)nhz | ((unsigned)nlz << 16);
    } else {           // k = 8..15 (13..15 zero)
        pa.x = (unsigned)lz | ((unsigned)h2 << 16);
        pa.y = (unsigned)l2 | (ONE << 16);
        pa.z = ONE;
        pa.w = 0u;
        pb.x = (unsigned)nhz | (ONE << 16);
        pb.y = ONE | ((unsigned)h2 << 16);
        pb.z = (unsigned)l2;
        pb.w = 0u;
    }
    size_t off = ((size_t)b * NFRAG + f) * 64 + lane;
    (cloud ? aT : aS)[off] = pa;
    (cloud ? bT : bS)[off] = pb;
}

// ---- scan: 32x32 MFMA, RF=4, double-buffered stages, paired min3 ----
__global__ __launch_bounds__(256, 2) void scan_kernel(
    const uint4* __restrict__ aS, const uint4* __restrict__ bS,
    const uint4* __restrict__ aT, const uint4* __restrict__ bT,
    float* __restrict__ part)   // part[dir][b][cg][row]
{
    __shared__ uint4 bsh[2][CFRAGS * 64];       // 2 x 16 KB
    const int tid = threadIdx.x;
    const int lane = tid & 63, wave = tid >> 6;
    const int rb = blockIdx.x, b = blockIdx.y;
    const int dir = blockIdx.z >> 2, cg = blockIdx.z & (NCHG - 1);

    const uint4* afr = dir ? aT : aS;   // rows = queries
    const uint4* bfr = dir ? bS : bT;   // cols = database

    // this wave's A frags (registers for the whole sweep)
    const uint4* asrc = afr + ((size_t)b * NFRAG + rb * (WAVES * RF) + wave * RF) * 64 + lane;
    bf16x8 afrag[RF];
#pragma unroll
    for (int r = 0; r < RF; r++) {
        uint4 t = asrc[r * 64];
        afrag[r] = *(bf16x8*)&t;
    }

    // stage 0 preload (1024 uint4 = 16 KB per stage, 4 per thread)
    const uint4* bbase = bfr + ((size_t)b * NFRAG + cg * (NSTAGE * CFRAGS)) * 64;
    uint4 pf[4];
#pragma unroll
    for (int j = 0; j < 4; j++) pf[j] = bbase[tid + j * 256];
#pragma unroll
    for (int j = 0; j < 4; j++) bsh[0][tid + j * 256] = pf[j];

    f32x16 vmin[RF];
#pragma unroll
    for (int r = 0; r < RF; r++)
#pragma unroll
        for (int i = 0; i < 16; i++) vmin[r][i] = 1e30f;
    f32x16 zero = {};
    __syncthreads();

    for (int s = 0; s < NSTAGE; s++) {
        const int cur = s & 1;
        if (s + 1 < NSTAGE) {
            const uint4* bn = bbase + (size_t)(s + 1) * CFRAGS * 64;
#pragma unroll
            for (int j = 0; j < 4; j++) pf[j] = bn[tid + j * 256];
        }
        for (int t = 0; t < CFRAGS; t += 2) {
            bf16x8 b0 = *(bf16x8*)&bsh[cur][t * 64 + lane];
            bf16x8 b1 = *(bf16x8*)&bsh[cur][(t + 1) * 64 + lane];
#pragma unroll
            for (int r = 0; r < RF; r++) {
                f32x16 dA = __builtin_amdgcn_mfma_f32_32x32x16_bf16(afrag[r], b0, zero, 0, 0, 0);
                f32x16 dB = __builtin_amdgcn_mfma_f32_32x32x16_bf16(afrag[r], b1, zero, 0, 0, 0);
#pragma unroll
                for (int i = 0; i < 16; i++)
                    vmin[r][i] = fminf(fminf(dA[i], dB[i]), vmin[r][i]);  // v_min3_f32
            }
        }
        if (s + 1 < NSTAGE) {
            __syncthreads();    // all waves done reading buf[cur^1]'s old data
#pragma unroll
            for (int j = 0; j < 4; j++) bsh[cur ^ 1][tid + j * 256] = pf[j];
            __syncthreads();    // writes visible before next stage's reads
        }
    }

    // finalize: min across the 32 col-lanes (xor bits 0-4 stay within half)
    const int half = lane >> 5;
#pragma unroll
    for (int r = 0; r < RF; r++) {
#pragma unroll
        for (int i = 0; i < 16; i++) {
            float v = vmin[r][i];
            v = fminf(v, __shfl_xor(v, 16, 64));
            v = fminf(v, __shfl_xor(v, 8, 64));
            v = fminf(v, __shfl_xor(v, 4, 64));
            v = fminf(v, __shfl_xor(v, 2, 64));
            v = fminf(v, __shfl_xor(v, 1, 64));
            if ((lane & 31) == 0) {
                int row = rb * (WAVES * RF * 32) + (wave * RF + r) * 32
                        + (i & 3) + 8 * (i >> 2) + 4 * half;
                part[((size_t)(dir * BB + b) * NCHG + cg) * NP + row] = v;
            }
        }
    }
}

// ---- reduce: min over column groups, weight, sum, atomicAdd ----
__global__ __launch_bounds__(256) void reduce_kernel(
    const float* __restrict__ weights, const float* __restrict__ part,
    float* __restrict__ out)
{
    int tid = threadIdx.x;
    int gid = blockIdx.x * 256 + tid;       // 0 .. 65535
    int dir = gid >> 15;
    int r   = gid & 32767;
    int b   = r >> 13;
    int q   = r & (NP - 1);

    const float* p = part + ((size_t)(dir * BB + b) * NCHG) * NP + q;
    float mn = 1e30f;
#pragma unroll
    for (int i = 0; i < NCHG; i++) mn = fminf(mn, p[(size_t)i * NP]);
    float w = dir ? 1.0f : weights[b * NP + q];
    float v = mn * w * (1.0f / BB);
#pragma unroll
    for (int off = 32; off; off >>= 1) v += __shfl_down(v, off, 64);
    __shared__ float ls[4];
    if ((tid & 63) == 0) ls[tid >> 6] = v;
    __syncthreads();
    if (tid == 0) atomicAdd(out, ls[0] + ls[1] + ls[2] + ls[3]);
}

extern "C" void kernel_launch(void* const* d_in, const int* in_sizes, int n_in,
                              void* d_out, int out_size, void* d_ws, size_t ws_size,
                              hipStream_t stream) {
    const float* src = (const float*)d_in[0];   // (B, N, 3)
    const float* tgt = (const float*)d_in[1];   // (B, M, 3)
    const float* wgt = (const float*)d_in[2];   // (B, N)
    float* out = (float*)d_out;

    char* ws = (char*)d_ws;
    const size_t FRAG_BYTES = (size_t)BB * NFRAG * 64 * 16;   // 1 MB each
    uint4* aS = (uint4*)(ws + 0 * FRAG_BYTES);
    uint4* bS = (uint4*)(ws + 1 * FRAG_BYTES);
    uint4* aT = (uint4*)(ws + 2 * FRAG_BYTES);
    uint4* bT = (uint4*)(ws + 3 * FRAG_BYTES);
    float* part = (float*)(ws + 4 * FRAG_BYTES);              // 1 MB

    prep_kernel<<<dim3(512), dim3(256), 0, stream>>>(src, tgt, aS, bS, aT, bT, out);
    scan_kernel<<<dim3(RBLOCKS, BB, 2 * NCHG), dim3(256), 0, stream>>>(aS, bS, aT, bT, part);
    reduce_kernel<<<dim3(256), dim3(256), 0, stream>>>(wgt, part, out);
}

// Round 6
// 95.861 us; speedup vs baseline: 1.0108x; 1.0108x over previous
//
#include <hip/hip_runtime.h>

// Weighted Chamfer, B=4, N=M=8192, D=3, fp32 in/out.
// out = (1/B)*[ sum_b sum_n w*min_m d2 + sum_b sum_m min_n d2 ]
//
// One v_mfma_f32_32x32x16_bf16 yields a 32x32 tile of d2 = s2 + t2 - 2 s.t
// via K-slot packing with split-bf16 compensation (verified rounds 2-5):
//   k0-8: {hs,hs,ls}x * {-2ht,-2lt,-2ht}x per dim; k9-10: {h,l}(s2)*1;
//   k11-12: 1*{h,l}(t2); k13-15: zero.  Error ~1e-5 (threshold 5.76).
// C/D layout (m74/m101): col=lane&31, row=(reg&3)+8*(reg>>2)+4*(lane>>5).
//
// Round 6: back to 4 waves/SIMD (r5's (256,2) halved TLP -> latency-bound).
// RF=2 + launch_bounds(256,4) with ~95 live VGPRs so the compiler keeps the
// MFMA C/D and vmin in ARCH VGPRs (r3's VGPR_Count=56 proved AGPR-split =
// v_accvgpr round-trip on every min3, 3-5x VALU tax). Single 32 KB LDS stage
// per block (NCHG=8) -> ONE barrier per block; explicit 1-iter ds prefetch.

typedef short bf16x8 __attribute__((ext_vector_type(8)));
typedef float f32x16 __attribute__((ext_vector_type(16)));

#define BB 4
#define NP 8192
#define NFRAG (NP / 32)          // 256 32-row fragments per batch
#define RF 2                     // row-frags per wave (64 rows)
#define WAVES 4                  // 256 rows per block
#define RBLOCKS 32               // 8192 / 256
#define CFRAGS 32                // frags per block stage (1024 cols, 32 KB)
#define NCHG 8                   // column groups (8192 / 1024)

__device__ __forceinline__ unsigned short bf16r(float x) {
    unsigned u = __float_as_uint(x);
    unsigned r = u + 0x7FFFu + ((u >> 16) & 1u);
    return (unsigned short)(r >> 16);
}
__device__ __forceinline__ float bf16f(unsigned short h) {
    return __uint_as_float(((unsigned)h) << 16);
}

// ---- prep: A-pack and B-pack (32x32x16 fragment layout) for both clouds ----
__global__ __launch_bounds__(256) void prep_kernel(
    const float* __restrict__ src, const float* __restrict__ tgt,
    uint4* __restrict__ aS, uint4* __restrict__ bS,
    uint4* __restrict__ aT, uint4* __restrict__ bT,
    float* __restrict__ out)
{
    int gid = blockIdx.x * 256 + threadIdx.x;   // 2*4*256*64 = 131072
    if (gid == 0) out[0] = 0.0f;
    int cloud = gid >> 16;
    int rem   = gid & 65535;
    int b     = rem >> 14;
    int f     = (rem >> 6) & (NFRAG - 1);
    int lane  = rem & 63;
    int half  = lane >> 5;
    int p     = f * 32 + (lane & 31);

    const float* c = cloud ? tgt : src;
    size_t base = ((size_t)b * NP + p) * 3;
    float x = c[base + 0], y = c[base + 1], z = c[base + 2];
    float n2 = x * x + y * y + z * z;

    unsigned short hx = bf16r(x), lx = bf16r(x - bf16f(hx));
    unsigned short hy = bf16r(y), ly = bf16r(y - bf16f(hy));
    unsigned short hz = bf16r(z), lz = bf16r(z - bf16f(hz));
    unsigned short h2 = bf16r(n2), l2 = bf16r(n2 - bf16f(h2));
    unsigned short nhx = bf16r(-2.f * bf16f(hx)), nlx = bf16r(-2.f * bf16f(lx));
    unsigned short nhy = bf16r(-2.f * bf16f(hy)), nly = bf16r(-2.f * bf16f(ly));
    unsigned short nhz = bf16r(-2.f * bf16f(hz)), nlz = bf16r(-2.f * bf16f(lz));
    const unsigned ONE = 0x3F80u;

    uint4 pa, pb;
    if (half == 0) {   // k = 0..7
        pa.x = (unsigned)hx | ((unsigned)hx << 16);
        pa.y = (unsigned)lx | ((unsigned)hy << 16);
        pa.z = (unsigned)hy | ((unsigned)ly << 16);
        pa.w = (unsigned)hz | ((unsigned)hz << 16);
        pb.x = (unsigned)nhx | ((unsigned)nlx << 16);
        pb.y = (unsigned)nhx | ((unsigned)nhy << 16);
        pb.z = (unsigned)nly | ((unsigned)nhy << 16);
        pb.w = (unsigned)nhz | ((unsigned)nlz << 16);
    } else {           // k = 8..15 (13..15 zero)
        pa.x = (unsigned)lz | ((unsigned)h2 << 16);
        pa.y = (unsigned)l2 | (ONE << 16);
        pa.z = ONE;
        pa.w = 0u;
        pb.x = (unsigned)nhz | (ONE << 16);
        pb.y = ONE | ((unsigned)h2 << 16);
        pb.z = (unsigned)l2;
        pb.w = 0u;
    }
    size_t off = ((size_t)b * NFRAG + f) * 64 + lane;
    (cloud ? aT : aS)[off] = pa;
    (cloud ? bT : bS)[off] = pb;
}

// ---- scan: one barrier per block; RF=2; ds prefetch; paired min3 ----
__global__ __launch_bounds__(256, 4) void scan_kernel(
    const uint4* __restrict__ aS, const uint4* __restrict__ bS,
    const uint4* __restrict__ aT, const uint4* __restrict__ bT,
    float* __restrict__ part)   // part[dir][b][cg][row]
{
    __shared__ uint4 bsh[CFRAGS * 64];          // 32 KB, single stage
    const int tid = threadIdx.x;
    const int lane = tid & 63, wave = tid >> 6;
    const int rb = blockIdx.x, b = blockIdx.y;
    const int dir = blockIdx.z >> 3, cg = blockIdx.z & (NCHG - 1);

    const uint4* afr = dir ? aT : aS;   // rows = queries
    const uint4* bfr = dir ? bS : bT;   // cols = database

    // stage this column group's 32 B-frags (8 uint4/thread, coalesced)
    const uint4* bsrc = bfr + ((size_t)b * NFRAG + cg * CFRAGS) * 64;
#pragma unroll
    for (int j = 0; j < 8; j++) bsh[tid + j * 256] = bsrc[tid + j * 256];

    // this wave's A frags
    const uint4* asrc = afr + ((size_t)b * NFRAG + rb * (WAVES * RF) + wave * RF) * 64 + lane;
    bf16x8 afrag[RF];
#pragma unroll
    for (int r = 0; r < RF; r++) {
        uint4 t = asrc[r * 64];
        afrag[r] = *(bf16x8*)&t;
    }

    f32x16 vmin[RF];
#pragma unroll
    for (int r = 0; r < RF; r++)
#pragma unroll
        for (int i = 0; i < 16; i++) vmin[r][i] = 1e30f;
    f32x16 zero = {};
    __syncthreads();                            // the block's ONLY barrier

    // software-pipelined sweep: prefetch next frag pair while computing current
    bf16x8 nb0 = *(bf16x8*)&bsh[0 * 64 + lane];
    bf16x8 nb1 = *(bf16x8*)&bsh[1 * 64 + lane];
    for (int t = 0; t < CFRAGS; t += 2) {
        bf16x8 b0 = nb0, b1 = nb1;
        if (t + 2 < CFRAGS) {
            nb0 = *(bf16x8*)&bsh[(t + 2) * 64 + lane];
            nb1 = *(bf16x8*)&bsh[(t + 3) * 64 + lane];
        }
#pragma unroll
        for (int r = 0; r < RF; r++) {
            f32x16 dA = __builtin_amdgcn_mfma_f32_32x32x16_bf16(afrag[r], b0, zero, 0, 0, 0);
            f32x16 dB = __builtin_amdgcn_mfma_f32_32x32x16_bf16(afrag[r], b1, zero, 0, 0, 0);
#pragma unroll
            for (int i = 0; i < 16; i++)
                vmin[r][i] = fminf(fminf(dA[i], dB[i]), vmin[r][i]);  // v_min3_f32
        }
    }

    // finalize: min across the 32 col-lanes (xor bits 0-4 stay within half)
    const int half = lane >> 5;
#pragma unroll
    for (int r = 0; r < RF; r++) {
#pragma unroll
        for (int i = 0; i < 16; i++) {
            float v = vmin[r][i];
            v = fminf(v, __shfl_xor(v, 16, 64));
            v = fminf(v, __shfl_xor(v, 8, 64));
            v = fminf(v, __shfl_xor(v, 4, 64));
            v = fminf(v, __shfl_xor(v, 2, 64));
            v = fminf(v, __shfl_xor(v, 1, 64));
            if ((lane & 31) == 0) {
                int row = rb * (WAVES * RF * 32) + (wave * RF + r) * 32
                        + (i & 3) + 8 * (i >> 2) + 4 * half;
                part[((size_t)(dir * BB + b) * NCHG + cg) * NP + row] = v;
            }
        }
    }
}

// ---- reduce: min over column groups, weight, sum, atomicAdd ----
__global__ __launch_bounds__(256) void reduce_kernel(
    const float* __restrict__ weights, const float* __restrict__ part,
    float* __restrict__ out)
{
    int tid = threadIdx.x;
    int gid = blockIdx.x * 256 + tid;       // 0 .. 65535
    int dir = gid >> 15;
    int r   = gid & 32767;
    int b   = r >> 13;
    int q   = r & (NP - 1);

    const float* p = part + ((size_t)(dir * BB + b) * NCHG) * NP + q;
    float mn = 1e30f;
#pragma unroll
    for (int i = 0; i < NCHG; i++) mn = fminf(mn, p[(size_t)i * NP]);
    float w = dir ? 1.0f : weights[b * NP + q];
    float v = mn * w * (1.0f / BB);
#pragma unroll
    for (int off = 32; off; off >>= 1) v += __shfl_down(v, off, 64);
    __shared__ float ls[4];
    if ((tid & 63) == 0) ls[tid >> 6] = v;
    __syncthreads();
    if (tid == 0) atomicAdd(out, ls[0] + ls[1] + ls[2] + ls[3]);
}

extern "C" void kernel_launch(void* const* d_in, const int* in_sizes, int n_in,
                              void* d_out, int out_size, void* d_ws, size_t ws_size,
                              hipStream_t stream) {
    const float* src = (const float*)d_in[0];   // (B, N, 3)
    const float* tgt = (const float*)d_in[1];   // (B, M, 3)
    const float* wgt = (const float*)d_in[2];   // (B, N)
    float* out = (float*)d_out;

    char* ws = (char*)d_ws;
    const size_t FRAG_BYTES = (size_t)BB * NFRAG * 64 * 16;   // 1 MB each
    uint4* aS = (uint4*)(ws + 0 * FRAG_BYTES);
    uint4* bS = (uint4*)(ws + 1 * FRAG_BYTES);
    uint4* aT = (uint4*)(ws + 2 * FRAG_BYTES);
    uint4* bT = (uint4*)(ws + 3 * FRAG_BYTES);
    float* part = (float*)(ws + 4 * FRAG_BYTES);              // 2 MB

    prep_kernel<<<dim3(512), dim3(256), 0, stream>>>(src, tgt, aS, bS, aT, bT, out);
    scan_kernel<<<dim3(RBLOCKS, BB, 2 * NCHG), dim3(256), 0, stream>>>(aS, bS, aT, bT, part);
    reduce_kernel<<<dim3(256), dim3(256), 0, stream>>>(wgt, part, out);
}

// Round 7
// 89.378 us; speedup vs baseline: 1.0841x; 1.0725x over previous
//
#include <hip/hip_runtime.h>

// Weighted Chamfer, B=4, N=M=8192, D=3, fp32 in/out.
// out = (1/B)*[ sum_b sum_n w*min_m d2 + sum_b sum_m min_n d2 ]
//
// One v_mfma_f32_32x32x16_bf16 yields a 32x32 tile of d2 = s2 + t2 - 2 s.t
// via K-slot packing with split-bf16 compensation (verified rounds 2-6):
//   k0-8: {hs,hs,ls}x * {-2ht,-2lt,-2ht}x per dim; k9-10: {h,l}(s2)*1;
//   k11-12: 1*{h,l}(t2); k13-15: zero.  Error ~1e-5 (threshold 5.76).
// C/D layout (m74/m101): col=lane&31, row=(reg&3)+8*(reg>>2)+4*(lane>>5).
//
// Round 7: (a) fat blocks — 1024 threads (16 waves, 4/SIMD), grid 256 = 1
// block/CU, 1024 rows x 2048 cols each; r4<->r6 A/B priced per-block fixed
// cost at ~4000 cyc, so pay it once per CU. (b) asm("":"+v") pins on MFMA
// results + vmin accumulators force arch-VGPR allocation (r3's VGPR=56
// proved the compiler's AGPR-split costs 3-5x VALU on the min3 path).

typedef short bf16x8 __attribute__((ext_vector_type(8)));
typedef float f32x16 __attribute__((ext_vector_type(16)));

#define BB 4
#define NP 8192
#define NFRAG (NP / 32)          // 256 32-row fragments per batch
#define RF 2                     // row-frags per wave (64 rows)
#define WAVES 16                 // 1024 threads -> 1024 rows per block
#define RBLOCKS 8                // 8192 / 1024
#define CFRAGS 32                // frags per LDS stage (1024 cols, 32 KB)
#define NSTG 2                   // stages per block -> 2048 cols
#define NCHG 4                   // column groups (8192 / 2048)

__device__ __forceinline__ unsigned short bf16r(float x) {
    unsigned u = __float_as_uint(x);
    unsigned r = u + 0x7FFFu + ((u >> 16) & 1u);
    return (unsigned short)(r >> 16);
}
__device__ __forceinline__ float bf16f(unsigned short h) {
    return __uint_as_float(((unsigned)h) << 16);
}

// ---- prep: A-pack and B-pack (32x32x16 fragment layout) for both clouds ----
__global__ __launch_bounds__(256) void prep_kernel(
    const float* __restrict__ src, const float* __restrict__ tgt,
    uint4* __restrict__ aS, uint4* __restrict__ bS,
    uint4* __restrict__ aT, uint4* __restrict__ bT,
    float* __restrict__ out)
{
    int gid = blockIdx.x * 256 + threadIdx.x;   // 2*4*256*64 = 131072
    if (gid == 0) out[0] = 0.0f;
    int cloud = gid >> 16;
    int rem   = gid & 65535;
    int b     = rem >> 14;
    int f     = (rem >> 6) & (NFRAG - 1);
    int lane  = rem & 63;
    int half  = lane >> 5;
    int p     = f * 32 + (lane & 31);

    const float* c = cloud ? tgt : src;
    size_t base = ((size_t)b * NP + p) * 3;
    float x = c[base + 0], y = c[base + 1], z = c[base + 2];
    float n2 = x * x + y * y + z * z;

    unsigned short hx = bf16r(x), lx = bf16r(x - bf16f(hx));
    unsigned short hy = bf16r(y), ly = bf16r(y - bf16f(hy));
    unsigned short hz = bf16r(z), lz = bf16r(z - bf16f(hz));
    unsigned short h2 = bf16r(n2), l2 = bf16r(n2 - bf16f(h2));
    unsigned short nhx = bf16r(-2.f * bf16f(hx)), nlx = bf16r(-2.f * bf16f(lx));
    unsigned short nhy = bf16r(-2.f * bf16f(hy)), nly = bf16r(-2.f * bf16f(ly));
    unsigned short nhz = bf16r(-2.f * bf16f(hz)), nlz = bf16r(-2.f * bf16f(lz));
    const unsigned ONE = 0x3F80u;

    uint4 pa, pb;
    if (half == 0) {   // k = 0..7
        pa.x = (unsigned)hx | ((unsigned)hx << 16);
        pa.y = (unsigned)lx | ((unsigned)hy << 16);
        pa.z = (unsigned)hy | ((unsigned)ly << 16);
        pa.w = (unsigned)hz | ((unsigned)hz << 16);
        pb.x = (unsigned)nhx | ((unsigned)nlx << 16);
        pb.y = (unsigned)nhx | ((unsigned)nhy << 16);
        pb.z = (unsigned)nly | ((unsigned)nhy << 16);
        pb.w = (unsigned)nhz | ((unsigned)nlz << 16);
    } else {           // k = 8..15 (13..15 zero)
        pa.x = (unsigned)lz | ((unsigned)h2 << 16);
        pa.y = (unsigned)l2 | (ONE << 16);
        pa.z = ONE;
        pa.w = 0u;
        pb.x = (unsigned)nhz | (ONE << 16);
        pb.y = ONE | ((unsigned)h2 << 16);
        pb.z = (unsigned)l2;
        pb.w = 0u;
    }
    size_t off = ((size_t)b * NFRAG + f) * 64 + lane;
    (cloud ? aT : aS)[off] = pa;
    (cloud ? bT : bS)[off] = pb;
}

// ---- scan: 1 block/CU, 1024 rows x 2048 cols, VGPR-pinned min3 sweep ----
__global__ __launch_bounds__(1024, 4) void scan_kernel(
    const uint4* __restrict__ aS, const uint4* __restrict__ bS,
    const uint4* __restrict__ aT, const uint4* __restrict__ bT,
    float* __restrict__ part)   // part[dir][b][cg][row]
{
    __shared__ uint4 bsh[CFRAGS * 64];          // 32 KB, one stage at a time
    const int tid = threadIdx.x;
    const int lane = tid & 63, wave = tid >> 6;
    const int rb = blockIdx.x, b = blockIdx.y;
    const int dir = blockIdx.z >> 2, cg = blockIdx.z & (NCHG - 1);

    const uint4* afr = dir ? aT : aS;   // rows = queries
    const uint4* bfr = dir ? bS : bT;   // cols = database

    // issue all global loads up front: stage0, stage1 prefetch, A-frags
    const uint4* bbase = bfr + ((size_t)b * NFRAG + cg * (NSTG * CFRAGS)) * 64;
    uint4 s0a = bbase[tid], s0b = bbase[tid + 1024];
    uint4 s1a = bbase[2048 + tid], s1b = bbase[2048 + tid + 1024];

    const uint4* asrc = afr + ((size_t)b * NFRAG + rb * (WAVES * RF) + wave * RF) * 64 + lane;
    bf16x8 afrag[RF];
#pragma unroll
    for (int r = 0; r < RF; r++) {
        uint4 t = asrc[r * 64];
        afrag[r] = *(bf16x8*)&t;
    }

    bsh[tid] = s0a; bsh[tid + 1024] = s0b;

    f32x16 vmin[RF];
#pragma unroll
    for (int r = 0; r < RF; r++)
#pragma unroll
        for (int i = 0; i < 16; i++) vmin[r][i] = 1e30f;
    f32x16 zero = {};
    __syncthreads();

#pragma unroll
    for (int s = 0; s < NSTG; s++) {
        for (int t = 0; t < CFRAGS; t += 2) {
            bf16x8 b0 = *(bf16x8*)&bsh[t * 64 + lane];
            bf16x8 b1 = *(bf16x8*)&bsh[(t + 1) * 64 + lane];
#pragma unroll
            for (int r = 0; r < RF; r++) {
                f32x16 dA = __builtin_amdgcn_mfma_f32_32x32x16_bf16(afrag[r], b0, zero, 0, 0, 0);
                f32x16 dB = __builtin_amdgcn_mfma_f32_32x32x16_bf16(afrag[r], b1, zero, 0, 0, 0);
                asm("" : "+v"(dA), "+v"(dB));          // pin D to arch VGPRs
#pragma unroll
                for (int i = 0; i < 16; i++)
                    vmin[r][i] = fminf(fminf(dA[i], dB[i]), vmin[r][i]);  // v_min3_f32
                asm("" : "+v"(vmin[r]));               // pin accumulator
            }
        }
        if (s == 0) {
            __syncthreads();
            bsh[tid] = s1a; bsh[tid + 1024] = s1b;
            __syncthreads();
        }
    }

    // finalize: min across the 32 col-lanes (xor bits 0-4 stay within half)
    const int half = lane >> 5;
#pragma unroll
    for (int r = 0; r < RF; r++) {
#pragma unroll
        for (int i = 0; i < 16; i++) {
            float v = vmin[r][i];
            v = fminf(v, __shfl_xor(v, 16, 64));
            v = fminf(v, __shfl_xor(v, 8, 64));
            v = fminf(v, __shfl_xor(v, 4, 64));
            v = fminf(v, __shfl_xor(v, 2, 64));
            v = fminf(v, __shfl_xor(v, 1, 64));
            if ((lane & 31) == 0) {
                int row = rb * (WAVES * RF * 32) + (wave * RF + r) * 32
                        + (i & 3) + 8 * (i >> 2) + 4 * half;
                part[((size_t)(dir * BB + b) * NCHG + cg) * NP + row] = v;
            }
        }
    }
}

// ---- reduce: min over column groups, weight, sum, atomicAdd ----
__global__ __launch_bounds__(256) void reduce_kernel(
    const float* __restrict__ weights, const float* __restrict__ part,
    float* __restrict__ out)
{
    int tid = threadIdx.x;
    int gid = blockIdx.x * 256 + tid;       // 0 .. 65535
    int dir = gid >> 15;
    int r   = gid & 32767;
    int b   = r >> 13;
    int q   = r & (NP - 1);

    const float* p = part + ((size_t)(dir * BB + b) * NCHG) * NP + q;
    float mn = 1e30f;
#pragma unroll
    for (int i = 0; i < NCHG; i++) mn = fminf(mn, p[(size_t)i * NP]);
    float w = dir ? 1.0f : weights[b * NP + q];
    float v = mn * w * (1.0f / BB);
#pragma unroll
    for (int off = 32; off; off >>= 1) v += __shfl_down(v, off, 64);
    __shared__ float ls[4];
    if ((tid & 63) == 0) ls[tid >> 6] = v;
    __syncthreads();
    if (tid == 0) atomicAdd(out, ls[0] + ls[1] + ls[2] + ls[3]);
}

extern "C" void kernel_launch(void* const* d_in, const int* in_sizes, int n_in,
                              void* d_out, int out_size, void* d_ws, size_t ws_size,
                              hipStream_t stream) {
    const float* src = (const float*)d_in[0];   // (B, N, 3)
    const float* tgt = (const float*)d_in[1];   // (B, M, 3)
    const float* wgt = (const float*)d_in[2];   // (B, N)
    float* out = (float*)d_out;

    char* ws = (char*)d_ws;
    const size_t FRAG_BYTES = (size_t)BB * NFRAG * 64 * 16;   // 1 MB each
    uint4* aS = (uint4*)(ws + 0 * FRAG_BYTES);
    uint4* bS = (uint4*)(ws + 1 * FRAG_BYTES);
    uint4* aT = (uint4*)(ws + 2 * FRAG_BYTES);
    uint4* bT = (uint4*)(ws + 3 * FRAG_BYTES);
    float* part = (float*)(ws + 4 * FRAG_BYTES);              // 1 MB

    prep_kernel<<<dim3(512), dim3(256), 0, stream>>>(src, tgt, aS, bS, aT, bT, out);
    scan_kernel<<<dim3(RBLOCKS, BB, 2 * NCHG), dim3(1024), 0, stream>>>(aS, bS, aT, bT, part);
    reduce_kernel<<<dim3(256), dim3(256), 0, stream>>>(wgt, part, out);
}

// Round 8
// 83.923 us; speedup vs baseline: 1.1546x; 1.0650x over previous
//
#include <hip/hip_runtime.h>

// Weighted Chamfer, B=4, N=M=8192, D=3, fp32 in/out.
// out = (1/B)*[ sum_b sum_n w*min_m d2 + sum_b sum_m min_n d2 ]
//
// One v_mfma_f32_32x32x16_bf16 yields a 32x32 tile of d2 = s2 + t2 - 2 s.t
// via K-slot packing with split-bf16 compensation (verified rounds 2-7):
//   k0-8: {hs,hs,ls}x * {-2ht,-2lt,-2ht}x per dim; k9-10: {h,l}(s2)*1;
//   k11-12: 1*{h,l}(t2); k13-15: zero.  Error ~1e-5 (threshold 5.76).
// C/D layout (m74/m101): col=lane&31, row=(reg&3)+8*(reg>>2)+4*(lane>>5).
//
// Round 8: TRANSPOSED operands. DB points are the A operand (rows, staged in
// LDS); queries are the B operand (cols, register-resident). Since col=lane&31,
// every d2 a lane holds belongs to ONE query -> the running min is a per-lane
// SCALAR (vminq[rf]), finalize = 1 shfl_xor(32) + 1 min + 1 store (r7's
// finalize was 160 ds_bpermute + 160 v_min per wave - the unpriced ~2x).
// Accumulator file drops from RF*16 to RF regs -> ~70 live VGPRs, no AGPR risk.

typedef short bf16x8 __attribute__((ext_vector_type(8)));
typedef float f32x16 __attribute__((ext_vector_type(16)));

#define BB 4
#define NP 8192
#define NFRAG (NP / 32)          // 256 32-point fragments per batch
#define RF 4                     // query-frags per wave (128 queries)
#define WAVES 4                  // 256 threads; 512 queries per block
#define QBLOCKS 16               // 8192 / 512
#define CFRAGS 32                // DB frags per LDS stage (1024 pts, 32 KB)
#define NCHG 8                   // DB chunks (8192 / 1024)

__device__ __forceinline__ unsigned short bf16r(float x) {
    unsigned u = __float_as_uint(x);
    unsigned r = u + 0x7FFFu + ((u >> 16) & 1u);
    return (unsigned short)(r >> 16);
}
__device__ __forceinline__ float bf16f(unsigned short h) {
    return __uint_as_float(((unsigned)h) << 16);
}

// ---- prep: A-pack and B-pack (32x32x16 fragment layout) for both clouds ----
__global__ __launch_bounds__(256) void prep_kernel(
    const float* __restrict__ src, const float* __restrict__ tgt,
    uint4* __restrict__ aS, uint4* __restrict__ bS,
    uint4* __restrict__ aT, uint4* __restrict__ bT,
    float* __restrict__ out)
{
    int gid = blockIdx.x * 256 + threadIdx.x;   // 2*4*256*64 = 131072
    if (gid == 0) out[0] = 0.0f;
    int cloud = gid >> 16;
    int rem   = gid & 65535;
    int b     = rem >> 14;
    int f     = (rem >> 6) & (NFRAG - 1);
    int lane  = rem & 63;
    int half  = lane >> 5;
    int p     = f * 32 + (lane & 31);

    const float* c = cloud ? tgt : src;
    size_t base = ((size_t)b * NP + p) * 3;
    float x = c[base + 0], y = c[base + 1], z = c[base + 2];
    float n2 = x * x + y * y + z * z;

    unsigned short hx = bf16r(x), lx = bf16r(x - bf16f(hx));
    unsigned short hy = bf16r(y), ly = bf16r(y - bf16f(hy));
    unsigned short hz = bf16r(z), lz = bf16r(z - bf16f(hz));
    unsigned short h2 = bf16r(n2), l2 = bf16r(n2 - bf16f(h2));
    unsigned short nhx = bf16r(-2.f * bf16f(hx)), nlx = bf16r(-2.f * bf16f(lx));
    unsigned short nhy = bf16r(-2.f * bf16f(hy)), nly = bf16r(-2.f * bf16f(ly));
    unsigned short nhz = bf16r(-2.f * bf16f(hz)), nlz = bf16r(-2.f * bf16f(lz));
    const unsigned ONE = 0x3F80u;

    uint4 pa, pb;
    if (half == 0) {   // k = 0..7
        pa.x = (unsigned)hx | ((unsigned)hx << 16);
        pa.y = (unsigned)lx | ((unsigned)hy << 16);
        pa.z = (unsigned)hy | ((unsigned)ly << 16);
        pa.w = (unsigned)hz | ((unsigned)hz << 16);
        pb.x = (unsigned)nhx | ((unsigned)nlx << 16);
        pb.y = (unsigned)nhx | ((unsigned)nhy << 16);
        pb.z = (unsigned)nly | ((unsigned)nhy << 16);
        pb.w = (unsigned)nhz | ((unsigned)nlz << 16);
    } else {           // k = 8..15 (13..15 zero)
        pa.x = (unsigned)lz | ((unsigned)h2 << 16);
        pa.y = (unsigned)l2 | (ONE << 16);
        pa.z = ONE;
        pa.w = 0u;
        pb.x = (unsigned)nhz | (ONE << 16);
        pb.y = ONE | ((unsigned)h2 << 16);
        pb.z = (unsigned)l2;
        pb.w = 0u;
    }
    size_t off = ((size_t)b * NFRAG + f) * 64 + lane;
    (cloud ? aT : aS)[off] = pa;
    (cloud ? bT : bS)[off] = pb;
}

// ---- scan: DB rows from LDS, queries in regs, per-lane scalar running min ----
__global__ __launch_bounds__(256, 4) void scan_kernel(
    const uint4* __restrict__ aS, const uint4* __restrict__ bS,
    const uint4* __restrict__ aT, const uint4* __restrict__ bT,
    float* __restrict__ part)   // part[dir][b][ch][query]
{
    __shared__ uint4 ash[CFRAGS * 64];          // 32 KB DB stage
    const int tid = threadIdx.x;
    const int lane = tid & 63, wave = tid >> 6;
    const int qb = blockIdx.x, b = blockIdx.y;
    const int dir = blockIdx.z >> 3, ch = blockIdx.z & (NCHG - 1);

    // dir 0: queries = source (B-op bS), DB = target (A-op aT); dir 1 mirrored.
    const uint4* qfr = dir ? bT : bS;
    const uint4* dfr = dir ? aS : aT;

    // stage DB chunk (32 frags, 8 uint4/thread, coalesced)
    const uint4* dsrc = dfr + ((size_t)b * NFRAG + ch * CFRAGS) * 64;
#pragma unroll
    for (int j = 0; j < 8; j++) ash[tid + j * 256] = dsrc[tid + j * 256];

    // this wave's query fragments (B operand, registers all sweep)
    const uint4* qsrc = qfr + ((size_t)b * NFRAG + qb * (WAVES * RF) + wave * RF) * 64 + lane;
    bf16x8 qfrag[RF];
#pragma unroll
    for (int rf = 0; rf < RF; rf++) {
        uint4 t = qsrc[rf * 64];
        qfrag[rf] = *(bf16x8*)&t;
    }

    float vminq[RF];
#pragma unroll
    for (int rf = 0; rf < RF; rf++) vminq[rf] = 1e30f;
    f32x16 zero = {};
    __syncthreads();                            // the block's only barrier

    for (int t = 0; t < CFRAGS; t += 2) {
        bf16x8 a0 = *(bf16x8*)&ash[t * 64 + lane];
        bf16x8 a1 = *(bf16x8*)&ash[(t + 1) * 64 + lane];
#pragma unroll
        for (int rf = 0; rf < RF; rf++) {
            f32x16 dA = __builtin_amdgcn_mfma_f32_32x32x16_bf16(a0, qfrag[rf], zero, 0, 0, 0);
            f32x16 dB = __builtin_amdgcn_mfma_f32_32x32x16_bf16(a1, qfrag[rf], zero, 0, 0, 0);
#pragma unroll
            for (int i = 0; i < 16; i++)
                vminq[rf] = fminf(fminf(dA[i], dB[i]), vminq[rf]);  // v_min3_f32
        }
    }

    // finalize: lane^32 holds the other 16 DB rows of the same query column
    float* pbase = part + ((size_t)(dir * BB + b) * NCHG + ch) * NP
                 + qb * (WAVES * RF * 32) + wave * (RF * 32);
#pragma unroll
    for (int rf = 0; rf < RF; rf++) {
        float v = fminf(vminq[rf], __shfl_xor(vminq[rf], 32, 64));
        if (lane < 32) pbase[rf * 32 + lane] = v;
    }
}

// ---- reduce: min over DB chunks, weight, sum, atomicAdd ----
__global__ __launch_bounds__(256) void reduce_kernel(
    const float* __restrict__ weights, const float* __restrict__ part,
    float* __restrict__ out)
{
    int tid = threadIdx.x;
    int gid = blockIdx.x * 256 + tid;       // 0 .. 65535
    int dir = gid >> 15;
    int r   = gid & 32767;
    int b   = r >> 13;
    int q   = r & (NP - 1);

    const float* p = part + ((size_t)(dir * BB + b) * NCHG) * NP + q;
    float mn = 1e30f;
#pragma unroll
    for (int i = 0; i < NCHG; i++) mn = fminf(mn, p[(size_t)i * NP]);
    float w = dir ? 1.0f : weights[b * NP + q];
    float v = mn * w * (1.0f / BB);
#pragma unroll
    for (int off = 32; off; off >>= 1) v += __shfl_down(v, off, 64);
    __shared__ float ls[4];
    if ((tid & 63) == 0) ls[tid >> 6] = v;
    __syncthreads();
    if (tid == 0) atomicAdd(out, ls[0] + ls[1] + ls[2] + ls[3]);
}

extern "C" void kernel_launch(void* const* d_in, const int* in_sizes, int n_in,
                              void* d_out, int out_size, void* d_ws, size_t ws_size,
                              hipStream_t stream) {
    const float* src = (const float*)d_in[0];   // (B, N, 3)
    const float* tgt = (const float*)d_in[1];   // (B, M, 3)
    const float* wgt = (const float*)d_in[2];   // (B, N)
    float* out = (float*)d_out;

    char* ws = (char*)d_ws;
    const size_t FRAG_BYTES = (size_t)BB * NFRAG * 64 * 16;   // 1 MB each
    uint4* aS = (uint4*)(ws + 0 * FRAG_BYTES);
    uint4* bS = (uint4*)(ws + 1 * FRAG_BYTES);
    uint4* aT = (uint4*)(ws + 2 * FRAG_BYTES);
    uint4* bT = (uint4*)(ws + 3 * FRAG_BYTES);
    float* part = (float*)(ws + 4 * FRAG_BYTES);              // 2 MB

    prep_kernel<<<dim3(512), dim3(256), 0, stream>>>(src, tgt, aS, bS, aT, bT, out);
    scan_kernel<<<dim3(QBLOCKS, BB, 2 * NCHG), dim3(256), 0, stream>>>(aS, bS, aT, bT, part);
    reduce_kernel<<<dim3(256), dim3(256), 0, stream>>>(wgt, part, out);
}